// Round 9
// baseline (202.465 us; speedup 1.0000x reference)
//
#include <hip/hip_runtime.h>
#include <math.h>

// Problem constants
#define NPOS   65536        // 16*64*64 positions
#define NE     1024         // codebook size
#define EDIM   64
#define HW     4096         // 64*64
#define BETA   0.25

// Output layout (floats) in d_out, reference return order:
// loss(1), z_q_st(16*64*64*64), perplexity(1), min_encodings(65536*1024), indices(65536)
#define OUT_LOSS 0LL
#define OUT_ZQ   1LL
#define OUT_PERP 4194305LL
#define OUT_ENC  4194306LL
#define OUT_IDX  71303170LL

#define POSB 128            // positions per block
#define JT   128            // code-tile width (8 tiles cover 1024)

// numpy pairwise_sum for n=64 (8 accumulators, stride 8, tree combine) of squares.
__device__ __forceinline__ float pairwise_sum_sq64(const float v[64]) {
#pragma clang fp contract(off)
    float r[8];
#pragma unroll
    for (int k = 0; k < 8; ++k) r[k] = v[k] * v[k];
#pragma unroll
    for (int i = 8; i < 64; i += 8) {
#pragma unroll
        for (int k = 0; k < 8; ++k) {
            float s = v[i + k] * v[i + k];
            r[k] = r[k] + s;
        }
    }
    return ((r[0] + r[1]) + (r[2] + r[3])) + ((r[4] + r[5]) + (r[6] + r[7]));
}

// K0: codebook norms + transposed codebook + zero counts + zero loss accumulator
__global__ void vq_prep(const float* __restrict__ emb, float* __restrict__ enorm,
                        float* __restrict__ embT, int* __restrict__ counts,
                        double* __restrict__ lacc) {
    int t = blockIdx.x * 256 + threadIdx.x;   // 0..1023
    if (t < NE) {
        float v[64];
#pragma unroll
        for (int c = 0; c < 64; ++c) v[c] = emb[t * 64 + c];
        enorm[t] = pairwise_sum_sq64(v);
#pragma unroll
        for (int c = 0; c < 64; ++c) embT[c * NE + t] = v[c];  // coalesced
        counts[t] = 0;
    }
    if (t == 0) *lacc = 0.0;
}

// K1: main. grid = 512 blocks x 256 threads.
// LDS-tiled register-blocked GEMM. Thread tile = 8 pos x 8 codes; per-thread
// codes are STRIDED ({4*tcode+i} u {64+4*tcode+i}) so each e-read is a
// 16-lane x 16B b128 spanning 256B -> 2-way bank alias = free (was 4-way,
// 8.5M conflict cycles in R7). One-hot zero-fill moved to hipMemsetAsync;
// this kernel writes only the scattered 1.0 per position (+ z_q, idx, loss).
// Bit-exactness: each dot = single accumulator, sequential k FMA; dist and
// argmin order identical to verified R2-R7.
__global__ __launch_bounds__(256, 4)
void vq_main(const float* __restrict__ z, const float* __restrict__ emb,
             const float* __restrict__ embT, const float* __restrict__ enorm,
             int* __restrict__ counts, double* __restrict__ lacc,
             float* __restrict__ out) {
    __shared__ float z_lds[64 * POSB];      // [c][p]
    __shared__ float e_lds[64 * JT];        // [c][q]
    __shared__ float enorm_lds[NE];
    __shared__ float szn_lds[POSB];
    __shared__ float run_d[POSB];
    __shared__ int   run_j[POSB];

    const int tid   = threadIdx.x;
    const int tpos  = tid >> 4;       // 0..15 -> positions tpos*8..+7
    const int tcode = tid & 15;       // 0..15 -> codes {4t..4t+3} u {64+4t..+3}
    const int n0    = blockIdx.x * POSB;
    const int b     = n0 >> 12;
    const int hw0   = n0 & 4095;
    const int zbase = b * (64 * HW) + hw0;

    // ---- stage z tile (64 c x 128 pos), float4 both sides ----
#pragma unroll
    for (int it = 0; it < 8; ++it) {
        const int idx4 = it * 256 + tid;          // 0..2047 float4s
        const int c    = idx4 >> 5;               // 32 float4 per c-row
        const int p4   = idx4 & 31;
        const float4 v = *(const float4*)(z + zbase + c * HW + p4 * 4);
        *(float4*)(&z_lds[c * POSB + p4 * 4]) = v;
    }
    // ---- stage enorm + init running argmin ----
#pragma unroll
    for (int it = 0; it < 4; ++it) enorm_lds[it * 256 + tid] = enorm[it * 256 + tid];
    if (tid < POSB) { run_d[tid] = 3.4e38f; run_j[tid] = 0; }
    __syncthreads();

    // ---- szn per position from z_lds (bit-identical, numpy pairwise order) ----
    if (tid < POSB) {
#pragma clang fp contract(off)
        float r[8];
#pragma unroll
        for (int k = 0; k < 8; ++k) { float x = z_lds[k * POSB + tid]; r[k] = x * x; }
#pragma unroll
        for (int i = 8; i < 64; i += 8) {
#pragma unroll
            for (int k = 0; k < 8; ++k) {
                float x = z_lds[(i + k) * POSB + tid];
                float s = x * x;
                r[k] = r[k] + s;
            }
        }
        szn_lds[tid] = ((r[0] + r[1]) + (r[2] + r[3])) + ((r[4] + r[5]) + (r[6] + r[7]));
    }
    __syncthreads();

    // ---- main loop over 8 code tiles ----
    for (int jo = 0; jo < 8; ++jo) {
        const int j0 = jo * JT;

        // stage e tile (64 c x 128 codes) from transposed codebook
#pragma unroll
        for (int it = 0; it < 8; ++it) {
            const int idx4 = it * 256 + tid;
            const int c    = idx4 >> 5;
            const int q4   = idx4 & 31;
            const float4 v = *(const float4*)(embT + c * NE + j0 + q4 * 4);
            *(float4*)(&e_lds[c * JT + q4 * 4]) = v;
        }
        __syncthreads();

        float acc[8][8];
#pragma unroll
        for (int i = 0; i < 8; ++i)
#pragma unroll
            for (int u = 0; u < 8; ++u) acc[i][u] = 0.0f;

        // k-loop: sequential k, single accumulator per (pos,code) pair.
        // e-reads: b128 at tcode*16B (2-way alias, conflict-free) and +256B.
        // z-reads: 4 distinct addrs/wave, 16-lane broadcast, conflict-free.
#pragma unroll 2
        for (int c = 0; c < 64; ++c) {
            const float4 za = *(const float4*)(&z_lds[c * POSB + tpos * 8]);
            const float4 zb = *(const float4*)(&z_lds[c * POSB + tpos * 8 + 4]);
            const float4 ea = *(const float4*)(&e_lds[c * JT + tcode * 4]);
            const float4 eb = *(const float4*)(&e_lds[c * JT + 64 + tcode * 4]);
            const float zf[8] = {za.x, za.y, za.z, za.w, zb.x, zb.y, zb.z, zb.w};
            const float ef[8] = {ea.x, ea.y, ea.z, ea.w, eb.x, eb.y, eb.z, eb.w};
#pragma unroll
            for (int i = 0; i < 8; ++i)
#pragma unroll
                for (int u = 0; u < 8; ++u)
                    acc[i][u] = fmaf(zf[i], ef[u], acc[i][u]);
        }

        // distances + tie-correct argmin reduce
#pragma unroll
        for (int i = 0; i < 8; ++i) {
            const int p = tpos * 8 + i;
            const float sz = szn_lds[p];
            float bd = 3.4e38f;
            int   bj = 0;
            // ascending j within this thread: {jA..jA+3} then {jB..jB+3}
#pragma unroll
            for (int u = 0; u < 4; ++u) {
                const int j = j0 + tcode * 4 + u;
                const float dj = (sz + enorm_lds[j]) - 2.0f * acc[i][u];
                if (dj < bd) { bd = dj; bj = j; }
            }
#pragma unroll
            for (int u = 0; u < 4; ++u) {
                const int j = j0 + 64 + tcode * 4 + u;
                const float dj = (sz + enorm_lds[j]) - 2.0f * acc[i][4 + u];
                if (dj < bd) { bd = dj; bj = j; }
            }
            // reduce across the 16 tcode-lanes; ties -> lower j (lex-min)
#pragma unroll
            for (int m = 1; m < 16; m <<= 1) {
                const float od = __shfl_xor(bd, m, 64);
                const int   oj = __shfl_xor(bj, m, 64);
                if (od < bd || (od == bd && oj < bj)) { bd = od; bj = oj; }
            }
            if (tcode == 0) {
                // ascending tile order + strict < keeps earliest index on ties
                if (bd < run_d[p]) { run_d[p] = bd; run_j[p] = bj; }
            }
        }
        __syncthreads();   // e_lds reuse + run_* visibility
    }

    // ---- outputs ----
    if (tid < POSB) {
        const int j = run_j[tid];
        atomicAdd(&counts[j], 1);
        out[OUT_IDX + n0 + tid] = (float)j;            // indices as f32 values
        out[OUT_ENC + (long long)(n0 + tid) * NE + j] = 1.0f;  // scatter the one
    }

    // z_q_st = z + (z_q - z) (two rounded f32 ops, verified pattern).
    // thread: pos = tid&127, channels (tid>>7)*32 .. +31; z from z_lds (same bits).
    {
        const int pos = tid & 127;
        const int half = tid >> 7;              // 0 or 1
        const int myj = run_j[pos];
        double acc2 = 0.0;
#pragma unroll
        for (int k = 0; k < 32; ++k) {
            const int c = half * 32 + k;
            const float zc = z_lds[c * POSB + pos];
            const float ec = emb[myj * 64 + c];
            const float t  = __fsub_rn(ec, zc);   // z_q - z
            const float o  = __fadd_rn(zc, t);    // z + (z_q - z)
            out[OUT_ZQ + (long long)b * (64LL * HW) + (long long)c * HW + hw0 + pos] = o;
            const float s = __fmul_rn(t, t);      // (z_q - z)^2 rounded f32
            acc2 += (double)s;
        }
        // wave-level f64 reduce, one atomic per wave
#pragma unroll
        for (int off = 32; off > 0; off >>= 1) acc2 += __shfl_down(acc2, off);
        if ((tid & 63) == 0) atomicAdd(lacc, acc2);
    }
}

// K2: perplexity + loss finalize. 1 block x 1024 threads.
__global__ void vq_finalize(const int* __restrict__ counts,
                            const double* __restrict__ lacc,
                            float* __restrict__ out) {
    __shared__ float red[1024];
    const int t = threadIdx.x;
    const float p = (float)counts[t] * (1.0f / 65536.0f); // exact (count int, /2^16)
    const float term = p * logf(p + 1e-10f);
    red[t] = term;
    __syncthreads();
    for (int s = 512; s > 0; s >>= 1) {
        if (t < s) red[t] += red[t + s];
        __syncthreads();
    }
    if (t == 0) {
        out[OUT_PERP] = expf(-red[0]);
        out[OUT_LOSS] = (float)(BETA * (*lacc / 4194304.0));
    }
}

extern "C" void kernel_launch(void* const* d_in, const int* in_sizes, int n_in,
                              void* d_out, int out_size, void* d_ws, size_t ws_size,
                              hipStream_t stream) {
    const float* z   = (const float*)d_in[0];   // (16,64,64,64) f32
    const float* emb = (const float*)d_in[1];   // (1024,64) f32
    float* out = (float*)d_out;

    double* lacc  = (double*)d_ws;
    int*    cnts  = (int*)((char*)d_ws + 16);
    float*  enorm = (float*)((char*)d_ws + 16 + NE * sizeof(int));
    float*  embT  = (float*)((char*)d_ws + 16 + NE * sizeof(int) + NE * sizeof(float));

    // zero-fill the 268 MB one-hot region with a driver memset (graph-capturable,
    // re-executed every replay -> deterministic); vq_main scatters the 1.0s.
    hipMemsetAsync(out + OUT_ENC, 0, (size_t)NPOS * NE * sizeof(float), stream);

    vq_prep<<<4, 256, 0, stream>>>(emb, enorm, embT, cnts, lacc);
    vq_main<<<512, 256, 0, stream>>>(z, emb, embT, enorm, cnts, lacc, out);
    vq_finalize<<<1, 1024, 0, stream>>>(cnts, lacc, out);
}